// Round 11
// baseline (370.731 us; speedup 1.0000x reference)
//
#include <hip/hip_runtime.h>
#include <math.h>

#define N_NODES 100000
#define NBUCK ((N_NODES + 255) / 256)   // 391 buckets of 256 nodes (both src and dst partitions)
#define CAP 8192                        // slots per bucket (mean 4096, +64 sigma)
#define ACHUNK 1024                     // edges per pass-A block (r4/r9: bigger chunks or more
                                        // occupancy both regress via partition write-amp)
#define CPAD 16                         // counter pad: one bucket counter per 64B line (r10 theory:
                                        // 16 buckets/line x 1563 chunks = 23K serialized same-line
                                        // atomics = the 82us passA floor)

struct alignas(16) f4 { float v[4]; };
struct alignas(8) us4 { unsigned short v[4]; };

typedef __attribute__((ext_vector_type(8))) short s8;     // 8 bf16 (4 VGPRs) MFMA A/B frag
typedef __attribute__((ext_vector_type(4))) float f32x4;  // MFMA C/D frag
typedef __attribute__((ext_vector_type(2))) float f2;     // packed f32 pair

__device__ inline unsigned short f2bf(float x) {
    union { float f; unsigned int u; } v;
    v.f = x;
    unsigned int r = v.u + 0x7FFF + ((v.u >> 16) & 1);
    return (unsigned short)(r >> 16);
}

__device__ inline float bf2f(unsigned short h) {
    union { unsigned int u; float f; } v;
    v.u = ((unsigned int)h) << 16;
    return v.f;
}

// ---------------- K1: interleaved [dual bucketed edge partition] + layer-0 MFMA GEMM ----------
// r8/r10-proven form (ACHUNK=1024, (256,4), K=128 single stage) + CPAD-padded reserve counters.
__global__ __launch_bounds__(256, 4) void k_passA_gemm0(const int* __restrict__ src,
                                                        const int* __restrict__ dst,
                                                        int E, int nchunk, int S,
                                                        int* __restrict__ bcur,
                                                        int* __restrict__ bcurS,
                                                        int* __restrict__ packed,
                                                        unsigned char* __restrict__ packedS,
                                                        const float* __restrict__ A,
                                                        const float* __restrict__ W,
                                                        unsigned short* __restrict__ C,
                                                        int n) {
    __shared__ __align__(16) short As[64][136];   // [row][k] bf16, K=128, +8 pad (stride 272B)
    __shared__ __align__(16) short Wt[64][136];   // [col][k] bf16 (W transposed)

    const int tid = threadIdx.x;
    const int b = blockIdx.x;

    if ((b % S == 0) && (b / S < nchunk)) {
        int* hist = (int*)As;            // NBUCK
        int* cur = hist + NBUCK;         // NBUCK
        int* histS = cur + NBUCK;        // NBUCK
        int* curS = histS + NBUCK;       // NBUCK
        const int base = (b / S) * ACHUNK;
        const int lim = min(E, base + ACHUNK);

        for (int i = tid; i < NBUCK; i += 256) { hist[i] = 0; histS[i] = 0; }
        __syncthreads();
        for (int i = base + tid; i < lim; i += 256) {
            int s = src[i];
            int d = dst[i];
            atomicAdd(&hist[d >> 8], 1);     // LDS
            atomicAdd(&histS[s >> 8], 1);    // LDS
        }
        __syncthreads();
        for (int i = tid; i < NBUCK; i += 256) {
            int c = hist[i];
            cur[i] = (c > 0) ? atomicAdd(&bcur[i * CPAD], c) : 0;     // padded: own line per bucket
            int cS = histS[i];
            curS[i] = (cS > 0) ? atomicAdd(&bcurS[i * CPAD], cS) : 0; // padded
        }
        __syncthreads();
        for (int i = base + tid; i < lim; i += 256) {
            int s = src[i];
            int d = dst[i];
            int bk = d >> 8;
            int p = min(atomicAdd(&cur[bk], 1), CAP - 1);   // clamp: no OOB even on overflow
            packed[(size_t)bk * CAP + p] = (s << 8) | (d & 255);
            int bs = s >> 8;
            int q = min(atomicAdd(&curS[bs], 1), CAP - 1);  // clamp
            packedS[(size_t)bs * CAP + q] = (unsigned char)(s & 255);
        }
        return;
    }

    // ---- MFMA GEMM tile (64 rows x 64 cols, K=128) ----
    const int nA = min((b + S - 1) / S, nchunk);  // pass-A ids below b
    const int r0 = (b - nA) * 64;

    for (int i = tid; i < 64 * 128; i += 256) {
        int k = i >> 6;
        int c = i & 63;
        Wt[c][k] = (short)f2bf(W[k * 64 + c]);
    }
    for (int i = tid * 4; i < 64 * 128; i += 1024) {
        int r = i >> 7;
        int c = i & 127;
        f4 v;
        if (r0 + r < n) {
            v = *(const f4*)&A[(size_t)(r0 + r) * 128 + c];
        } else {
            v.v[0] = v.v[1] = v.v[2] = v.v[3] = 0.0f;
        }
        us4 o;
#pragma unroll
        for (int j = 0; j < 4; ++j) o.v[j] = f2bf(v.v[j]);
        *(us4*)&As[r][c] = o;
    }
    __syncthreads();

    const int w = tid >> 6;        // wave: rows [w*16, w*16+16)
    const int lane = tid & 63;
    const int rsel = lane & 15;    // row selector (A) / col selector (B)
    const int g = lane >> 4;       // k-group

    f32x4 acc[4];
#pragma unroll
    for (int nt = 0; nt < 4; ++nt) acc[nt] = (f32x4){0.f, 0.f, 0.f, 0.f};

#pragma unroll
    for (int ks = 0; ks < 4; ++ks) {
        int kb = ks * 32 + g * 8;
        s8 a = *(const s8*)&As[w * 16 + rsel][kb];
#pragma unroll
        for (int nt = 0; nt < 4; ++nt) {
            s8 bb = *(const s8*)&Wt[nt * 16 + rsel][kb];
            acc[nt] = __builtin_amdgcn_mfma_f32_16x16x32_bf16(a, bb, acc[nt], 0, 0, 0);
        }
    }

    int rb = r0 + w * 16 + g * 4;
#pragma unroll
    for (int nt = 0; nt < 4; ++nt) {
        int col = nt * 16 + rsel;
#pragma unroll
        for (int j = 0; j < 4; ++j) {
            int row = rb + j;
            if (row < n) C[(size_t)row * 64 + col] = f2bf(acc[nt][j]);
        }
    }
}

// ---------------- K2: per-bucket CSR build + norms + fused layer-0 ns scale ----------------
__global__ __launch_bounds__(256) void k_passB(const int* __restrict__ bcur,
                                               const int* __restrict__ bcurS,
                                               const int* __restrict__ packed,
                                               const unsigned char* __restrict__ packedS,
                                               int* __restrict__ csr_src,
                                               int* __restrict__ row_beg,
                                               int* __restrict__ row_end,
                                               float* __restrict__ ns,
                                               float* __restrict__ nd,
                                               unsigned int* __restrict__ Hd,
                                               int n) {
    __shared__ int cnt[256];
    __shared__ int cur[256];
    __shared__ int cntS[256];
    __shared__ int wsum[4];
    __shared__ float nss[256];

    const int b = blockIdx.x;
    const int tid = threadIdx.x;
    const int lane = tid & 63;
    const int wid = tid >> 6;
    const int n0 = b * 256;
    const int nn = min(256, n - n0);
    const int m = min(bcur[b * CPAD], CAP);      // padded counters
    const int mS = min(bcurS[b * CPAD], CAP);
    const int* pk = packed + (size_t)b * CAP;
    const unsigned char* pkS = packedS + (size_t)b * CAP;

    cnt[tid] = 0;
    cntS[tid] = 0;
    __syncthreads();
    for (int i = tid; i < m; i += 256) atomicAdd(&cnt[pk[i] & 255], 1);
    for (int i = tid; i < mS; i += 256) atomicAdd(&cntS[(int)pkS[i]], 1);
    __syncthreads();
    int c = cnt[tid];
    int v = c;
#pragma unroll
    for (int off = 1; off < 64; off <<= 1) {
        int t = __shfl_up(v, off);
        if (lane >= off) v += t;
    }
    if (lane == 63) wsum[wid] = v;
    __syncthreads();
    int basex = 0;
#pragma unroll
    for (int w = 0; w < 4; ++w)
        if (w < wid) basex += wsum[w];
    int excl = basex + v - c;
    cur[tid] = excl;
    if (tid < nn) {
        int vtx = n0 + tid;
        int beg = b * CAP + excl;
        row_beg[vtx] = beg;
        row_end[vtx] = beg + c;
        nd[vtx] = (c > 0) ? rsqrtf((float)c) : 0.0f;
        int dg = cntS[tid];
        float s = (dg > 0) ? rsqrtf((float)dg) : 0.0f;
        ns[vtx] = s;
        nss[tid] = s;
    }
    __syncthreads();
    for (int i = tid; i < m; i += 256) {
        int w = pk[i];
        int vv = w & 255;
        int p = atomicAdd(&cur[vv], 1);  // LDS
        csr_src[(size_t)b * CAP + p] = w >> 8;
    }
    for (int i = tid; i < nn * 32; i += 256) {
        int r = i >> 5;
        float s = nss[r];
        size_t di = (size_t)(n0 + r) * 32 + (i & 31);
        unsigned int u = Hd[di];
        float lo = bf2f((unsigned short)(u & 0xffffu)) * s;
        float hi = bf2f((unsigned short)(u >> 16)) * s;
        Hd[di] = (unsigned int)f2bf(lo) | ((unsigned int)f2bf(hi) << 16);
    }
}

// ---------------- fused agg + relu + log_softmax + NEXT-layer (G@W)*ns -> bf16 Hout ----------
// r10's 8-lane-group agg (proven) + in-register GEMM epilogue replacing k_gemm_scale:
// after log-softmax the node's G-row lives in x[0..7] per lane (lane q owns cols q*8..q*8+7).
// out[c] = sum_k G[k]*W[k][c]: loop r,j over the 8x8 (lane,elem) grid; broadcast gk within the
// group (shfl width 8, uniform flow), FMA against W[r*8+j][q*8..+7] staged in LDS f32.
// Deletes both gemm dispatches and the 51MB G round-trip; f32 FMA (more precise than the
// bf16-MFMA path it replaces). OUTW = valid W cols (64 for W1, 40 for W2; rest zero-padded).
// Hout MUST differ from H (double-buffered by caller).
template <int OUTW>
__global__ __launch_bounds__(256) void k_agg_gemm(const int* __restrict__ row_beg,
                                                  const int* __restrict__ row_end,
                                                  const int* __restrict__ csr_src,
                                                  const unsigned short* __restrict__ H,
                                                  const float* __restrict__ nd,
                                                  const float* __restrict__ bias,
                                                  const float* __restrict__ W,
                                                  const float* __restrict__ ns,
                                                  unsigned short* __restrict__ Hout,
                                                  int n) {
    __shared__ float Wl[64][64];                 // 16KB: W rows k=0..63 (cols >= OUTW zero)

    const int tid = threadIdx.x;
    for (int i = tid; i < 64 * 64; i += 256) {
        int k = i >> 6;
        int c = i & 63;
        Wl[k][c] = (c < OUTW) ? W[k * OUTW + c] : 0.0f;
    }
    __syncthreads();                             // before any possible return

    const int node = blockIdx.x * 32 + (tid >> 3);
    const int q = tid & 7;
    if (node >= n) return;                       // group-uniform

    const int beg = row_beg[node];
    const int end = row_end[node];

    f2 a01 = {0.f, 0.f}, a23 = {0.f, 0.f}, a45 = {0.f, 0.f}, a67 = {0.f, 0.f};
    const unsigned int* Hd = (const unsigned int*)H;     // dword view; row = 32 dwords
    const unsigned int pb = (unsigned)q * 4u;

    for (int i = beg; i < end; i += 8) {
        int cnt = min(8, end - i);               // group-uniform
        int idx = (q < cnt) ? csr_src[i + q] : 0;
#pragma unroll
        for (int j = 0; j < 8; ++j) {
            int s = __shfl(idx, j, 8);           // within-group broadcast, uniform flow (r7 rule)
            if (j < cnt) {                       // group-uniform guard
                unsigned int off = (unsigned)s * 32u + pb;
                uint2 q0 = *(const uint2*)(Hd + off);
                uint2 q1 = *(const uint2*)(Hd + off + 2);
                f2 v;
                v.x = __uint_as_float(q0.x << 16);
                v.y = __uint_as_float(q0.x & 0xffff0000u);
                a01 += v;
                v.x = __uint_as_float(q0.y << 16);
                v.y = __uint_as_float(q0.y & 0xffff0000u);
                a23 += v;
                v.x = __uint_as_float(q1.x << 16);
                v.y = __uint_as_float(q1.x & 0xffff0000u);
                a45 += v;
                v.x = __uint_as_float(q1.y << 16);
                v.y = __uint_as_float(q1.y & 0xffff0000u);
                a67 += v;
            }
        }
    }

    float acc[8];
    acc[0] = a01.x; acc[1] = a01.y; acc[2] = a23.x; acc[3] = a23.y;
    acc[4] = a45.x; acc[5] = a45.y; acc[6] = a67.x; acc[7] = a67.y;

    const float ndv = nd[node];
    float x[8];
    float m = -INFINITY;
#pragma unroll
    for (int j = 0; j < 8; ++j) {
        float xx = acc[j] * ndv + bias[q * 8 + j];
        xx = fmaxf(xx, 0.0f);                    // fused layers always RELU
        x[j] = xx;
        m = fmaxf(m, xx);
    }
    m = fmaxf(m, __shfl_xor(m, 1));
    m = fmaxf(m, __shfl_xor(m, 2));
    m = fmaxf(m, __shfl_xor(m, 4));
    float ssum = 0.0f;
#pragma unroll
    for (int j = 0; j < 8; ++j) ssum += __expf(x[j] - m);
    ssum += __shfl_xor(ssum, 1);
    ssum += __shfl_xor(ssum, 2);
    ssum += __shfl_xor(ssum, 4);
    const float lg = __logf(ssum);
#pragma unroll
    for (int j = 0; j < 8; ++j) x[j] = (x[j] - m) - lg;   // G row (log-softmax), in regs

    // ---- G @ W epilogue: out[q*8..q*8+7] = sum_{r,j} G[r*8+j] * W[r*8+j][q*8..+7] ----
    f4 o0 = {0.f, 0.f, 0.f, 0.f}, o1 = {0.f, 0.f, 0.f, 0.f};
    for (int r = 0; r < 8; ++r) {
#pragma unroll
        for (int j = 0; j < 8; ++j) {
            float gk = __shfl(x[j], r, 8);       // group broadcast, uniform flow
            const f4 w0 = *(const f4*)&Wl[r * 8 + j][q * 8];
            const f4 w1 = *(const f4*)&Wl[r * 8 + j][q * 8 + 4];
#pragma unroll
            for (int t = 0; t < 4; ++t) o0.v[t] += gk * w0.v[t];
#pragma unroll
            for (int t = 0; t < 4; ++t) o1.v[t] += gk * w1.v[t];
        }
    }
    const float sv = ns[node];
    unsigned int d0 = (unsigned)f2bf(o0.v[0] * sv) | ((unsigned)f2bf(o0.v[1] * sv) << 16);
    unsigned int d1 = (unsigned)f2bf(o0.v[2] * sv) | ((unsigned)f2bf(o0.v[3] * sv) << 16);
    unsigned int d2 = (unsigned)f2bf(o1.v[0] * sv) | ((unsigned)f2bf(o1.v[1] * sv) << 16);
    unsigned int d3 = (unsigned)f2bf(o1.v[2] * sv) | ((unsigned)f2bf(o1.v[3] * sv) << 16);
    uint4 pack = make_uint4(d0, d1, d2, d3);
    *(uint4*)&Hout[(size_t)node * 64 + q * 8] = pack;    // 16B aligned (row 128B, q*16B)
}

// ---------------- final fused CSR aggregate + (*nd + b) + log_softmax (r10-proven) ------------
template <int HS, int DA, bool RELU>
__global__ __launch_bounds__(256) void k_agg_post(const int* __restrict__ row_beg,
                                                  const int* __restrict__ row_end,
                                                  const int* __restrict__ csr_src,
                                                  const unsigned short* __restrict__ H,
                                                  const float* __restrict__ nd,
                                                  const float* __restrict__ b,
                                                  float* __restrict__ Out,
                                                  int n) {
    const int tid = threadIdx.x;
    const int node = blockIdx.x * 32 + (tid >> 3);
    const int q = tid & 7;
    if (node >= n) return;                       // group-uniform

    const int beg = row_beg[node];
    const int end = row_end[node];

    f2 a01 = {0.f, 0.f}, a23 = {0.f, 0.f}, a45 = {0.f, 0.f}, a67 = {0.f, 0.f};
    const unsigned int* Hd = (const unsigned int*)H;
    const unsigned int pb = (unsigned)q * 4u;

    for (int i = beg; i < end; i += 8) {
        int cnt = min(8, end - i);
        int idx = (q < cnt) ? csr_src[i + q] : 0;
#pragma unroll
        for (int j = 0; j < 8; ++j) {
            int s = __shfl(idx, j, 8);           // within-group broadcast, uniform flow
            if (j < cnt) {
                unsigned int off = (unsigned)s * (unsigned)(HS / 2) + pb;
                uint2 q0 = *(const uint2*)(Hd + off);
                uint2 q1 = *(const uint2*)(Hd + off + 2);
                f2 v;
                v.x = __uint_as_float(q0.x << 16);
                v.y = __uint_as_float(q0.x & 0xffff0000u);
                a01 += v;
                v.x = __uint_as_float(q0.y << 16);
                v.y = __uint_as_float(q0.y & 0xffff0000u);
                a23 += v;
                v.x = __uint_as_float(q1.x << 16);
                v.y = __uint_as_float(q1.x & 0xffff0000u);
                a45 += v;
                v.x = __uint_as_float(q1.y << 16);
                v.y = __uint_as_float(q1.y & 0xffff0000u);
                a67 += v;
            }
        }
    }

    float acc[8];
    acc[0] = a01.x; acc[1] = a01.y; acc[2] = a23.x; acc[3] = a23.y;
    acc[4] = a45.x; acc[5] = a45.y; acc[6] = a67.x; acc[7] = a67.y;

    float ndv = nd[node];
    float x[8];
    float m = -INFINITY;
    const bool colsOK = (q * 8 < DA);
#pragma unroll
    for (int j = 0; j < 8; ++j) {
        if (colsOK) {
            float xx = acc[j] * ndv + b[q * 8 + j];
            if (RELU) xx = fmaxf(xx, 0.0f);
            x[j] = xx;
            m = fmaxf(m, xx);
        } else {
            x[j] = -INFINITY;
        }
    }
    m = fmaxf(m, __shfl_xor(m, 1));
    m = fmaxf(m, __shfl_xor(m, 2));
    m = fmaxf(m, __shfl_xor(m, 4));
    float ssum = 0.0f;
#pragma unroll
    for (int j = 0; j < 8; ++j)
        if (colsOK) ssum += __expf(x[j] - m);
    ssum += __shfl_xor(ssum, 1);
    ssum += __shfl_xor(ssum, 2);
    ssum += __shfl_xor(ssum, 4);

    if (colsOK) {
        float lg = __logf(ssum);
        f4 o0, o1;
#pragma unroll
        for (int j = 0; j < 4; ++j) o0.v[j] = (x[j] - m) - lg;
#pragma unroll
        for (int j = 0; j < 4; ++j) o1.v[j] = (x[4 + j] - m) - lg;
        *(f4*)&Out[(size_t)node * DA + q * 8] = o0;
        *(f4*)&Out[(size_t)node * DA + q * 8 + 4] = o1;
    }
}

extern "C" void kernel_launch(void* const* d_in, const int* in_sizes, int n_in,
                              void* d_out, int out_size, void* d_ws, size_t ws_size,
                              hipStream_t stream) {
    const float* feats = (const float*)d_in[0];
    const int* src = (const int*)d_in[1];
    const int* dst = (const int*)d_in[2];
    const float* W0 = (const float*)d_in[3];
    const float* b0 = (const float*)d_in[4];
    const float* W1 = (const float*)d_in[5];
    const float* b1 = (const float*)d_in[6];
    const float* W2 = (const float*)d_in[7];
    const float* b2 = (const float*)d_in[8];
    float* out = (float*)d_out;

    const int N = N_NODES;
    const int E = in_sizes[1];
    const int GT = (N + 63) / 64;                       // 1563 gemm tiles
    const int NCHUNK = (E + ACHUNK - 1) / ACHUNK;       // 1563 pass-A chunks
    const int grid1 = GT + NCHUNK;
    int S = grid1 / NCHUNK;                             // interleave stride (=2)
    if (S < 1) S = 1;

    // workspace layout (~57 MB)
    float* ns = (float*)d_ws;                           // N
    float* nd = ns + N;                                 // N
    unsigned short* HbA = (unsigned short*)(nd + N);    // N*64 bf16
    unsigned short* HbB = HbA + (size_t)N * 64;         // N*64 bf16 (double buffer, was G)
    int* packed = (int*)(HbB + (size_t)N * 64);         // NBUCK*CAP ints
    int* csr_src = packed + (size_t)NBUCK * CAP;        // NBUCK*CAP ints
    int* row_beg = csr_src + (size_t)NBUCK * CAP;       // N
    int* row_end = row_beg + N;                         // N
    int* bcur = row_end + N;                            // NBUCK*CPAD (line-padded counters)
    int* bcurS = bcur + NBUCK * CPAD;                   // NBUCK*CPAD
    unsigned char* packedS = (unsigned char*)(bcurS + NBUCK * CPAD); // NBUCK*CAP bytes

    hipMemsetAsync(bcur, 0, (size_t)2 * NBUCK * CPAD * sizeof(int), stream);

    // 1) interleaved dual-partition + layer-0 MFMA GEMM (unscaled) -> HbA
    k_passA_gemm0<<<grid1, 256, 0, stream>>>(src, dst, E, NCHUNK, S, bcur, bcurS,
                                             packed, packedS, feats, W0, HbA, N);

    // 2) per-bucket CSR build + norms + fused layer-0 ns scale (HbA *= ns)
    k_passB<<<NBUCK, 256, 0, stream>>>(bcur, bcurS, packed, packedS, csr_src,
                                       row_beg, row_end, ns, nd, (unsigned int*)HbA, N);

    const int agg_blocks = (N + 31) / 32;               // 8-lane group per node, 32 nodes/block

    // 3) layer-0 agg + relu + logsoftmax + (G@W1)*ns -> HbB
    k_agg_gemm<64><<<agg_blocks, 256, 0, stream>>>(row_beg, row_end, csr_src, HbA, nd, b0,
                                                   W1, ns, HbB, N);

    // 4) layer-1 agg + relu + logsoftmax + (G@W2pad)*ns -> HbA (cols 40..63 zero)
    k_agg_gemm<40><<<agg_blocks, 256, 0, stream>>>(row_beg, row_end, csr_src, HbB, nd, b1,
                                                   W2, ns, HbA, N);

    // 5) layer-2 agg + b2 + logsoftmax -> out (f32)
    k_agg_post<64, 40, false><<<agg_blocks, 256, 0, stream>>>(row_beg, row_end, csr_src, HbA,
                                                              nd, b2, out, N);
}

// Round 12
// 331.690 us; speedup vs baseline: 1.1177x; 1.1177x over previous
//
#include <hip/hip_runtime.h>
#include <math.h>

#define N_NODES 100000
#define NBUCK ((N_NODES + 255) / 256)   // 391 buckets of 256 nodes (both src and dst partitions)
#define CAP 8192                        // slots per bucket (mean 4096, +64 sigma)
#define ACHUNK 1024                     // edges per pass-A block.
// PARTITION EQUILIBRIUM LAW (r4/r9/r11, 3x confirmed): anything that increases scatter-phase
// concurrency (bigger chunks, more blocks/CU, faster reserve atomics via padded counters)
// increases concurrently-open partial bucket lines -> L2 mid-fill evictions -> WRITE_SIZE
// +30-35MB -> passA slower. The unpadded/1024/(256,4) point (82us, 43MB) is self-regulated.

struct alignas(16) f4 { float v[4]; };
struct alignas(8) us4 { unsigned short v[4]; };

typedef __attribute__((ext_vector_type(8))) short s8;     // 8 bf16 (4 VGPRs) MFMA A/B frag
typedef __attribute__((ext_vector_type(4))) float f32x4;  // MFMA C/D frag
typedef __attribute__((ext_vector_type(2))) float f2;     // packed f32 pair

__device__ inline unsigned short f2bf(float x) {
    union { float f; unsigned int u; } v;
    v.f = x;
    unsigned int r = v.u + 0x7FFF + ((v.u >> 16) & 1);
    return (unsigned short)(r >> 16);
}

__device__ inline float bf2f(unsigned short h) {
    union { unsigned int u; float f; } v;
    v.u = ((unsigned int)h) << 16;
    return v.f;
}

// ---------------- K1: interleaved [dual bucketed edge partition] + layer-0 MFMA GEMM ----------
// r10-proven form exactly (ACHUNK=1024, (256,4), K=128 single stage, UNPADDED counters).
__global__ __launch_bounds__(256, 4) void k_passA_gemm0(const int* __restrict__ src,
                                                        const int* __restrict__ dst,
                                                        int E, int nchunk, int S,
                                                        int* __restrict__ bcur,
                                                        int* __restrict__ bcurS,
                                                        int* __restrict__ packed,
                                                        unsigned char* __restrict__ packedS,
                                                        const float* __restrict__ A,
                                                        const float* __restrict__ W,
                                                        unsigned short* __restrict__ C,
                                                        int n) {
    __shared__ __align__(16) short As[64][136];   // [row][k] bf16, K=128, +8 pad (stride 272B)
    __shared__ __align__(16) short Wt[64][136];   // [col][k] bf16 (W transposed)

    const int tid = threadIdx.x;
    const int b = blockIdx.x;

    if ((b % S == 0) && (b / S < nchunk)) {
        int* hist = (int*)As;            // NBUCK
        int* cur = hist + NBUCK;         // NBUCK
        int* histS = cur + NBUCK;        // NBUCK
        int* curS = histS + NBUCK;       // NBUCK
        const int base = (b / S) * ACHUNK;
        const int lim = min(E, base + ACHUNK);

        for (int i = tid; i < NBUCK; i += 256) { hist[i] = 0; histS[i] = 0; }
        __syncthreads();
        for (int i = base + tid; i < lim; i += 256) {
            int s = src[i];
            int d = dst[i];
            atomicAdd(&hist[d >> 8], 1);     // LDS
            atomicAdd(&histS[s >> 8], 1);    // LDS
        }
        __syncthreads();
        for (int i = tid; i < NBUCK; i += 256) {
            int c = hist[i];
            cur[i] = (c > 0) ? atomicAdd(&bcur[i], c) : 0;     // hot-line global (the throttle)
            int cS = histS[i];
            curS[i] = (cS > 0) ? atomicAdd(&bcurS[i], cS) : 0;
        }
        __syncthreads();
        for (int i = base + tid; i < lim; i += 256) {
            int s = src[i];
            int d = dst[i];
            int bk = d >> 8;
            int p = min(atomicAdd(&cur[bk], 1), CAP - 1);   // clamp: no OOB even on overflow
            packed[(size_t)bk * CAP + p] = (s << 8) | (d & 255);
            int bs = s >> 8;
            int q = min(atomicAdd(&curS[bs], 1), CAP - 1);  // clamp
            packedS[(size_t)bs * CAP + q] = (unsigned char)(s & 255);
        }
        return;
    }

    // ---- MFMA GEMM tile (64 rows x 64 cols, K=128) ----
    const int nA = min((b + S - 1) / S, nchunk);  // pass-A ids below b
    const int r0 = (b - nA) * 64;

    for (int i = tid; i < 64 * 128; i += 256) {
        int k = i >> 6;
        int c = i & 63;
        Wt[c][k] = (short)f2bf(W[k * 64 + c]);
    }
    for (int i = tid * 4; i < 64 * 128; i += 1024) {
        int r = i >> 7;
        int c = i & 127;
        f4 v;
        if (r0 + r < n) {
            v = *(const f4*)&A[(size_t)(r0 + r) * 128 + c];
        } else {
            v.v[0] = v.v[1] = v.v[2] = v.v[3] = 0.0f;
        }
        us4 o;
#pragma unroll
        for (int j = 0; j < 4; ++j) o.v[j] = f2bf(v.v[j]);
        *(us4*)&As[r][c] = o;
    }
    __syncthreads();

    const int w = tid >> 6;        // wave: rows [w*16, w*16+16)
    const int lane = tid & 63;
    const int rsel = lane & 15;    // row selector (A) / col selector (B)
    const int g = lane >> 4;       // k-group

    f32x4 acc[4];
#pragma unroll
    for (int nt = 0; nt < 4; ++nt) acc[nt] = (f32x4){0.f, 0.f, 0.f, 0.f};

#pragma unroll
    for (int ks = 0; ks < 4; ++ks) {
        int kb = ks * 32 + g * 8;
        s8 a = *(const s8*)&As[w * 16 + rsel][kb];
#pragma unroll
        for (int nt = 0; nt < 4; ++nt) {
            s8 bb = *(const s8*)&Wt[nt * 16 + rsel][kb];
            acc[nt] = __builtin_amdgcn_mfma_f32_16x16x32_bf16(a, bb, acc[nt], 0, 0, 0);
        }
    }

    int rb = r0 + w * 16 + g * 4;
#pragma unroll
    for (int nt = 0; nt < 4; ++nt) {
        int col = nt * 16 + rsel;
#pragma unroll
        for (int j = 0; j < 4; ++j) {
            int row = rb + j;
            if (row < n) C[(size_t)row * 64 + col] = f2bf(acc[nt][j]);
        }
    }
}

// ---------------- K2: per-bucket CSR build + norms + fused layer-0 ns scale (proven) ---------
__global__ __launch_bounds__(256) void k_passB(const int* __restrict__ bcur,
                                               const int* __restrict__ bcurS,
                                               const int* __restrict__ packed,
                                               const unsigned char* __restrict__ packedS,
                                               int* __restrict__ csr_src,
                                               int* __restrict__ row_beg,
                                               int* __restrict__ row_end,
                                               float* __restrict__ ns,
                                               float* __restrict__ nd,
                                               unsigned int* __restrict__ Hd,
                                               int n) {
    __shared__ int cnt[256];
    __shared__ int cur[256];
    __shared__ int cntS[256];
    __shared__ int wsum[4];
    __shared__ float nss[256];

    const int b = blockIdx.x;
    const int tid = threadIdx.x;
    const int lane = tid & 63;
    const int wid = tid >> 6;
    const int n0 = b * 256;
    const int nn = min(256, n - n0);
    const int m = min(bcur[b], CAP);
    const int mS = min(bcurS[b], CAP);
    const int* pk = packed + (size_t)b * CAP;
    const unsigned char* pkS = packedS + (size_t)b * CAP;

    cnt[tid] = 0;
    cntS[tid] = 0;
    __syncthreads();
    for (int i = tid; i < m; i += 256) atomicAdd(&cnt[pk[i] & 255], 1);
    for (int i = tid; i < mS; i += 256) atomicAdd(&cntS[(int)pkS[i]], 1);
    __syncthreads();
    int c = cnt[tid];
    int v = c;
#pragma unroll
    for (int off = 1; off < 64; off <<= 1) {
        int t = __shfl_up(v, off);
        if (lane >= off) v += t;
    }
    if (lane == 63) wsum[wid] = v;
    __syncthreads();
    int basex = 0;
#pragma unroll
    for (int w = 0; w < 4; ++w)
        if (w < wid) basex += wsum[w];
    int excl = basex + v - c;
    cur[tid] = excl;
    if (tid < nn) {
        int vtx = n0 + tid;
        int beg = b * CAP + excl;
        row_beg[vtx] = beg;
        row_end[vtx] = beg + c;
        nd[vtx] = (c > 0) ? rsqrtf((float)c) : 0.0f;
        int dg = cntS[tid];
        float s = (dg > 0) ? rsqrtf((float)dg) : 0.0f;
        ns[vtx] = s;
        nss[tid] = s;
    }
    __syncthreads();
    for (int i = tid; i < m; i += 256) {
        int w = pk[i];
        int vv = w & 255;
        int p = atomicAdd(&cur[vv], 1);  // LDS
        csr_src[(size_t)b * CAP + p] = w >> 8;
    }
    for (int i = tid; i < nn * 32; i += 256) {
        int r = i >> 5;
        float s = nss[r];
        size_t di = (size_t)(n0 + r) * 32 + (i & 31);
        unsigned int u = Hd[di];
        float lo = bf2f((unsigned short)(u & 0xffffu)) * s;
        float hi = bf2f((unsigned short)(u >> 16)) * s;
        Hd[di] = (unsigned int)f2bf(lo) | ((unsigned int)f2bf(hi) << 16);
    }
}

// ---------------- MFMA GEMM (K=64): C = bf16((A @ W) * ns[row]), row stride 64 always --------
template <int OUT>
__global__ __launch_bounds__(256, 4) void k_gemm_scale(const float* __restrict__ A,
                                                       const float* __restrict__ W,
                                                       const float* __restrict__ ns,
                                                       unsigned short* __restrict__ C,
                                                       int n) {
    __shared__ __align__(16) short As[64][72];   // [row][k] bf16, +8 pad (stride 144B)
    __shared__ __align__(16) short Wt[64][72];   // [col][k] bf16

    const int tid = threadIdx.x;
    const int r0 = blockIdx.x * 64;

    for (int i = tid; i < 64 * 64; i += 256) {
        int k = i >> 6;
        int c = i & 63;
        float wv = (c < OUT) ? W[k * OUT + c] : 0.0f;
        Wt[c][k] = (short)f2bf(wv);
    }
    for (int i = tid * 4; i < 64 * 64; i += 1024) {
        int r = i >> 6;
        int c = i & 63;
        f4 v;
        if (r0 + r < n) {
            v = *(const f4*)&A[(size_t)(r0 + r) * 64 + c];
        } else {
            v.v[0] = v.v[1] = v.v[2] = v.v[3] = 0.0f;
        }
        us4 o;
#pragma unroll
        for (int j = 0; j < 4; ++j) o.v[j] = f2bf(v.v[j]);
        *(us4*)&As[r][c] = o;
    }
    __syncthreads();

    const int w = tid >> 6;
    const int lane = tid & 63;
    const int rsel = lane & 15;
    const int g = lane >> 4;

    f32x4 acc[4];
#pragma unroll
    for (int nt = 0; nt < 4; ++nt) acc[nt] = (f32x4){0.f, 0.f, 0.f, 0.f};

#pragma unroll
    for (int ks = 0; ks < 2; ++ks) {
        int kb = ks * 32 + g * 8;
        s8 a = *(const s8*)&As[w * 16 + rsel][kb];
#pragma unroll
        for (int nt = 0; nt < 4; ++nt) {
            s8 bb = *(const s8*)&Wt[nt * 16 + rsel][kb];
            acc[nt] = __builtin_amdgcn_mfma_f32_16x16x32_bf16(a, bb, acc[nt], 0, 0, 0);
        }
    }

    int rb = r0 + w * 16 + g * 4;
    float s4v[4];
#pragma unroll
    for (int j = 0; j < 4; ++j) s4v[j] = (rb + j < n) ? ns[rb + j] : 0.0f;
#pragma unroll
    for (int nt = 0; nt < 4; ++nt) {
        int col = nt * 16 + rsel;
#pragma unroll
        for (int j = 0; j < 4; ++j) {
            int row = rb + j;
            if (row < n) {
                float val = (col < OUT) ? acc[nt][j] * s4v[j] : 0.0f;
                C[(size_t)row * 64 + col] = f2bf(val);   // stride 64 always
            }
        }
    }
}

// ---------------- fused CSR aggregate + (*nd + b) + relu? + log_softmax: 8-lane groups -------
// r10-proven structure + STRIDE-16 BATCHES: both idx words loaded up front, 16 unrolled
// slots -> a mean-degree-16 node completes its whole gather in ONE iteration with ~32 loads
// in flight (r10 ran two dependent 8-edge batches). Halves the serial chain, doubles MLP.
// SHFL SAFETY (r7): shfl sources in reader's own 8-lane group, uniform flow, hoisted above
// the (group-uniform) per-slot guard.
template <int HS, int DA, bool RELU>
__global__ __launch_bounds__(256) void k_agg_post(const int* __restrict__ row_beg,
                                                  const int* __restrict__ row_end,
                                                  const int* __restrict__ csr_src,
                                                  const unsigned short* __restrict__ H,
                                                  const float* __restrict__ nd,
                                                  const float* __restrict__ b,
                                                  float* __restrict__ Out,
                                                  int n) {
    const int tid = threadIdx.x;
    const int node = blockIdx.x * 32 + (tid >> 3);
    const int q = tid & 7;
    if (node >= n) return;                       // group-uniform

    const int beg = row_beg[node];
    const int end = row_end[node];

    f2 a01 = {0.f, 0.f}, a23 = {0.f, 0.f}, a45 = {0.f, 0.f}, a67 = {0.f, 0.f};
    const unsigned int* Hd = (const unsigned int*)H;     // dword view; row = HS/2 dwords
    const unsigned int pb = (unsigned)q * 4u;

    for (int i = beg; i < end; i += 16) {
        int cnt = min(16, end - i);              // group-uniform
        int idx0 = (q < cnt) ? csr_src[i + q] : 0;
        int idx1 = (8 + q < cnt) ? csr_src[i + 8 + q] : 0;
#pragma unroll
        for (int j = 0; j < 16; ++j) {           // j compile-time (unrolled)
            int s = (j < 8) ? __shfl(idx0, j, 8) : __shfl(idx1, j - 8, 8);
            if (j < cnt) {                       // group-uniform guard
                unsigned int off = (unsigned)s * (unsigned)(HS / 2) + pb;
                uint2 q0 = *(const uint2*)(Hd + off);
                uint2 q1 = *(const uint2*)(Hd + off + 2);
                f2 v;
                v.x = __uint_as_float(q0.x << 16);
                v.y = __uint_as_float(q0.x & 0xffff0000u);
                a01 += v;
                v.x = __uint_as_float(q0.y << 16);
                v.y = __uint_as_float(q0.y & 0xffff0000u);
                a23 += v;
                v.x = __uint_as_float(q1.x << 16);
                v.y = __uint_as_float(q1.x & 0xffff0000u);
                a45 += v;
                v.x = __uint_as_float(q1.y << 16);
                v.y = __uint_as_float(q1.y & 0xffff0000u);
                a67 += v;
            }
        }
    }

    float acc[8];
    acc[0] = a01.x; acc[1] = a01.y; acc[2] = a23.x; acc[3] = a23.y;
    acc[4] = a45.x; acc[5] = a45.y; acc[6] = a67.x; acc[7] = a67.y;

    float ndv = nd[node];
    float x[8];
    float m = -INFINITY;
    const bool colsOK = (q * 8 < DA);            // group-divergent only for DA=40 (q>=5)
#pragma unroll
    for (int j = 0; j < 8; ++j) {
        if (colsOK) {
            float xx = acc[j] * ndv + b[q * 8 + j];
            if (RELU) xx = fmaxf(xx, 0.0f);
            x[j] = xx;
            m = fmaxf(m, xx);
        } else {
            x[j] = -INFINITY;
        }
    }
    m = fmaxf(m, __shfl_xor(m, 1));
    m = fmaxf(m, __shfl_xor(m, 2));
    m = fmaxf(m, __shfl_xor(m, 4));
    float ssum = 0.0f;
#pragma unroll
    for (int j = 0; j < 8; ++j)
        if (colsOK) ssum += __expf(x[j] - m);
    ssum += __shfl_xor(ssum, 1);
    ssum += __shfl_xor(ssum, 2);
    ssum += __shfl_xor(ssum, 4);

    if (colsOK) {
        float lg = __logf(ssum);
        f4 o0, o1;
#pragma unroll
        for (int j = 0; j < 4; ++j) o0.v[j] = (x[j] - m) - lg;
#pragma unroll
        for (int j = 0; j < 4; ++j) o1.v[j] = (x[4 + j] - m) - lg;
        *(f4*)&Out[(size_t)node * DA + q * 8] = o0;
        *(f4*)&Out[(size_t)node * DA + q * 8 + 4] = o1;
    }
}

extern "C" void kernel_launch(void* const* d_in, const int* in_sizes, int n_in,
                              void* d_out, int out_size, void* d_ws, size_t ws_size,
                              hipStream_t stream) {
    const float* feats = (const float*)d_in[0];
    const int* src = (const int*)d_in[1];
    const int* dst = (const int*)d_in[2];
    const float* W0 = (const float*)d_in[3];
    const float* b0 = (const float*)d_in[4];
    const float* W1 = (const float*)d_in[5];
    const float* b1 = (const float*)d_in[6];
    const float* W2 = (const float*)d_in[7];
    const float* b2 = (const float*)d_in[8];
    float* out = (float*)d_out;

    const int N = N_NODES;
    const int E = in_sizes[1];
    const int GT = (N + 63) / 64;                       // 1563 gemm tiles
    const int NCHUNK = (E + ACHUNK - 1) / ACHUNK;       // 1563 pass-A chunks
    const int grid1 = GT + NCHUNK;
    int S = grid1 / NCHUNK;                             // interleave stride (=2)
    if (S < 1) S = 1;

    // workspace layout (~69 MB)
    float* ns = (float*)d_ws;                           // N
    float* nd = ns + N;                                 // N
    unsigned short* Hb = (unsigned short*)(nd + N);     // N*64 bf16
    float* G = (float*)(Hb + (size_t)N * 64);           // N*64 fp32
    int* packed = (int*)(G + (size_t)N * 64);           // NBUCK*CAP ints
    int* csr_src = packed + (size_t)NBUCK * CAP;        // NBUCK*CAP ints
    int* row_beg = csr_src + (size_t)NBUCK * CAP;       // N
    int* row_end = row_beg + N;                         // N
    int* bcur = row_end + N;                            // NBUCK
    int* bcurS = bcur + NBUCK;                          // NBUCK
    unsigned char* packedS = (unsigned char*)(bcurS + NBUCK); // NBUCK*CAP bytes

    hipMemsetAsync(bcur, 0, (size_t)2 * NBUCK * sizeof(int), stream);

    // 1) interleaved dual-partition + layer-0 MFMA GEMM (unscaled)
    k_passA_gemm0<<<grid1, 256, 0, stream>>>(src, dst, E, NCHUNK, S, bcur, bcurS,
                                             packed, packedS, feats, W0, Hb, N);

    // 2) per-bucket CSR build + norms + fused layer-0 ns scale
    k_passB<<<NBUCK, 256, 0, stream>>>(bcur, bcurS, packed, packedS, csr_src,
                                       row_beg, row_end, ns, nd, (unsigned int*)Hb, N);

    const int agg_blocks = (N + 31) / 32;               // 8-lane group per node, 32 nodes/block

    // ---- layer 0 agg + relu + log_softmax -> G ----
    k_agg_post<64, 64, true><<<agg_blocks, 256, 0, stream>>>(row_beg, row_end, csr_src, Hb, nd, b0, G, N);

    // ---- layer 1 ----
    k_gemm_scale<64><<<GT, 256, 0, stream>>>(G, W1, ns, Hb, N);
    k_agg_post<64, 64, true><<<agg_blocks, 256, 0, stream>>>(row_beg, row_end, csr_src, Hb, nd, b1, G, N);

    // ---- layer 2 (H padded to stride 64; cols 40..63 zero) ----
    k_gemm_scale<40><<<GT, 256, 0, stream>>>(G, W2, ns, Hb, N);
    k_agg_post<64, 40, false><<<agg_blocks, 256, 0, stream>>>(row_beg, row_end, csr_src, Hb, nd, b2, out, N);
}